// Round 1
// baseline (878.241 us; speedup 1.0000x reference)
//
#include <hip/hip_runtime.h>

#define THREADS 128
#define BPB 8              // batches per block
#define NBATCH 131072

constexpr int XSTRIDE = 340;   // f32 per batch in LDS  (>= 21*16), stagger for banks
constexpr int YSTRIDE = 520;   // bf16 halves per batch (>= 32*16)
constexpr int ASTRIDE = 1032;  // bf16 halves per batch (>= 64*16)

static __device__ __forceinline__ unsigned short f2bf(float f) {
    unsigned int u = __float_as_uint(f);
    u += 0x7fffu + ((u >> 16) & 1u);     // round-to-nearest-even
    return (unsigned short)(u >> 16);
}
static __device__ __forceinline__ unsigned int pack2(float a, float b) {
    return (unsigned int)f2bf(a) | ((unsigned int)f2bf(b) << 16);
}
static __device__ __forceinline__ float lo2f(unsigned int u) { return __uint_as_float(u << 16); }
static __device__ __forceinline__ float hi2f(unsigned int u) { return __uint_as_float(u & 0xffff0000u); }

__global__ __launch_bounds__(THREADS, 3)
void peptide_fused(const float* __restrict__ x,
                   const float* __restrict__ w0,     // [32][21]
                   const float* __restrict__ attw,   // [15][32]
                   const float* __restrict__ attb,   // [15]
                   const float* __restrict__ w1,     // [64][32][3]
                   const float* __restrict__ cb1,    // [64]
                   const float* __restrict__ g1, const float* __restrict__ bt1,
                   const float* __restrict__ mn1, const float* __restrict__ vr1,
                   const float* __restrict__ w2,     // [20][64][3]
                   const float* __restrict__ cb2,    // [20]
                   const float* __restrict__ g2, const float* __restrict__ bt2,
                   const float* __restrict__ mn2, const float* __restrict__ vr2,
                   float* __restrict__ out)          // [B][20][11]
{
    // union: x (f32, stage 0-1) overlapped with a1 (bf16, stage 2-3); y separate
    __shared__ __align__(16) unsigned char smem[BPB*ASTRIDE*2 + BPB*YSTRIDE*2];
    float*          s_x  = reinterpret_cast<float*>(smem);
    unsigned short* s_a1 = reinterpret_cast<unsigned short*>(smem);
    unsigned short* s_y  = reinterpret_cast<unsigned short*>(smem + BPB*ASTRIDE*2);

    const int tid = threadIdx.x;
    const long long bb = (long long)blockIdx.x * BPB;

    // ---------- stage 0: load x -> LDS, rows padded to 16 ----------
    {
        const float* xg = x + bb * 315;
        for (int i = tid; i < BPB*315; i += THREADS) {
            int b = i / 315;
            int r = i - b*315;
            int k = r / 15;
            int l = r - k*15;
            s_x[b*XSTRIDE + k*16 + l] = xg[i];
        }
    }
    __syncthreads();

    // ---------- stage 1: conv0 (21->32) + attention softmax -> y (bf16) ----------
    {
        const int b  = tid >> 4;     // 0..7
        const int cc = tid & 15;     // handles channels cc and cc+16
        float h0[15], h1[15];
#pragma unroll
        for (int l = 0; l < 15; ++l) { h0[l] = 0.f; h1[l] = 0.f; }
        const float* xb = s_x + b*XSTRIDE;
#pragma unroll 3
        for (int k = 0; k < 21; ++k) {
            float4 A = *(const float4*)(xb + k*16 + 0);
            float4 Bv = *(const float4*)(xb + k*16 + 4);
            float4 C = *(const float4*)(xb + k*16 + 8);
            float4 D = *(const float4*)(xb + k*16 + 12);   // slot 15 garbage, unused
            float xv[16] = {A.x,A.y,A.z,A.w, Bv.x,Bv.y,Bv.z,Bv.w,
                            C.x,C.y,C.z,C.w, D.x,D.y,D.z,D.w};
            float wa = w0[cc*21 + k];
            float wb = w0[(cc+16)*21 + k];
#pragma unroll
            for (int l = 0; l < 15; ++l) {
                h0[l] = fmaf(wa, xv[l], h0[l]);
                h1[l] = fmaf(wb, xv[l], h1[l]);
            }
        }
        // logits: reduce attn_w[l,c]*h[c,l] over the 16 lanes (2 channels each)
        float lg[15];
#pragma unroll
        for (int l = 0; l < 15; ++l)
            lg[l] = attw[l*32 + cc]*h0[l] + attw[l*32 + cc + 16]*h1[l];
#pragma unroll
        for (int m = 1; m <= 8; m <<= 1) {
#pragma unroll
            for (int l = 0; l < 15; ++l) lg[l] += __shfl_xor(lg[l], m);
        }
#pragma unroll
        for (int l = 0; l < 15; ++l) lg[l] += attb[l];
        // softmax over L=15 (every lane redundantly, identical fp order)
        float mx = lg[0];
#pragma unroll
        for (int l = 1; l < 15; ++l) mx = fmaxf(mx, lg[l]);
        float s = 0.f;
#pragma unroll
        for (int l = 0; l < 15; ++l) { lg[l] = __expf(lg[l] - mx); s += lg[l]; }
        float inv = 1.f / s;
        float y0[15], y1[15];
#pragma unroll
        for (int l = 0; l < 15; ++l) {
            float a_ = lg[l]*inv;
            y0[l] = h0[l]*a_;
            y1[l] = h1[l]*a_;
        }
        unsigned short* yb = s_y + b*YSTRIDE;
        uint4 u;
        u.x = pack2(y0[0],y0[1]);  u.y = pack2(y0[2],y0[3]);
        u.z = pack2(y0[4],y0[5]);  u.w = pack2(y0[6],y0[7]);
        *(uint4*)(yb + cc*16) = u;
        u.x = pack2(y0[8],y0[9]);  u.y = pack2(y0[10],y0[11]);
        u.z = pack2(y0[12],y0[13]); u.w = pack2(y0[14], 0.f);
        *(uint4*)(yb + cc*16 + 8) = u;
        u.x = pack2(y1[0],y1[1]);  u.y = pack2(y1[2],y1[3]);
        u.z = pack2(y1[4],y1[5]);  u.w = pack2(y1[6],y1[7]);
        *(uint4*)(yb + (cc+16)*16) = u;
        u.x = pack2(y1[8],y1[9]);  u.y = pack2(y1[10],y1[11]);
        u.z = pack2(y1[12],y1[13]); u.w = pack2(y1[14], 0.f);
        *(uint4*)(yb + (cc+16)*16 + 8) = u;
    }
    __syncthreads();

    // ---------- stage 2: conv1 (32->64,k3) + bn1 + lrelu -> a1 (bf16, overwrites x) ----------
    {
        const int b = tid >> 4;
        const int j = tid & 15;     // handles o = j, j+16, j+32, j+48
        float acc[4][13];
#pragma unroll
        for (int m = 0; m < 4; ++m)
#pragma unroll
            for (int p = 0; p < 13; ++p) acc[m][p] = 0.f;
        const unsigned short* yb = s_y + b*YSTRIDE;
#pragma unroll 2
        for (int c = 0; c < 32; ++c) {
            uint4 r0 = *(const uint4*)(yb + c*16);
            uint4 r1 = *(const uint4*)(yb + c*16 + 8);
            float yv[15];
            yv[0]=lo2f(r0.x);  yv[1]=hi2f(r0.x);  yv[2]=lo2f(r0.y);  yv[3]=hi2f(r0.y);
            yv[4]=lo2f(r0.z);  yv[5]=hi2f(r0.z);  yv[6]=lo2f(r0.w);  yv[7]=hi2f(r0.w);
            yv[8]=lo2f(r1.x);  yv[9]=hi2f(r1.x);  yv[10]=lo2f(r1.y); yv[11]=hi2f(r1.y);
            yv[12]=lo2f(r1.z); yv[13]=hi2f(r1.z); yv[14]=lo2f(r1.w);
#pragma unroll
            for (int m = 0; m < 4; ++m) {
                const int o = m*16 + j;
                const float wA = w1[o*96 + c*3 + 0];
                const float wB = w1[o*96 + c*3 + 1];
                const float wC = w1[o*96 + c*3 + 2];
#pragma unroll
                for (int p = 0; p < 13; ++p)
                    acc[m][p] += wA*yv[p] + wB*yv[p+1] + wC*yv[p+2];
            }
        }
        unsigned short* ab = s_a1 + b*ASTRIDE;
#pragma unroll
        for (int m = 0; m < 4; ++m) {
            const int o = m*16 + j;
            const float bi = cb1[o];
            const float iv = g1[o] * rsqrtf(vr1[o] + 1e-5f);
            const float sh = bt1[o] - mn1[o]*iv;
            float z[13];
#pragma unroll
            for (int p = 0; p < 13; ++p) {
                float t = (acc[m][p] + bi)*iv + sh;
                z[p] = t > 0.f ? t : 0.01f*t;
            }
            uint4 u;
            u.x = pack2(z[0],z[1]);  u.y = pack2(z[2],z[3]);
            u.z = pack2(z[4],z[5]);  u.w = pack2(z[6],z[7]);
            *(uint4*)(ab + o*16) = u;
            u.x = pack2(z[8],z[9]);  u.y = pack2(z[10],z[11]);
            u.z = pack2(z[12],0.f);  u.w = 0u;
            *(uint4*)(ab + o*16 + 8) = u;
        }
    }
    __syncthreads();

    // ---------- stage 3: conv2 (64->20,k3) + bn2 + lrelu -> out ----------
    {
        const int wv   = tid >> 6;      // wave 0: q 0..15, wave 1: q 16..19
        const int lane = tid & 63;
        const int b    = lane >> 3;     // all 8 batches covered per wave
        const int qi   = lane & 7;
        const bool is0  = (wv == 0);
        const bool has0 = is0 || (qi < 4);
        const int q0 = is0 ? qi : (has0 ? (qi + 16) : 0);
        const int q1 = qi + 8;          // wave0 only
        float acc0[11], acc1[11];
#pragma unroll
        for (int p = 0; p < 11; ++p) { acc0[p] = 0.f; acc1[p] = 0.f; }
        const unsigned short* ab = s_a1 + b*ASTRIDE;
#pragma unroll 2
        for (int o = 0; o < 64; ++o) {
            uint4 r0 = *(const uint4*)(ab + o*16);
            uint4 r1 = *(const uint4*)(ab + o*16 + 8);
            float av[13];
            av[0]=lo2f(r0.x);  av[1]=hi2f(r0.x);  av[2]=lo2f(r0.y);  av[3]=hi2f(r0.y);
            av[4]=lo2f(r0.z);  av[5]=hi2f(r0.z);  av[6]=lo2f(r0.w);  av[7]=hi2f(r0.w);
            av[8]=lo2f(r1.x);  av[9]=hi2f(r1.x);  av[10]=lo2f(r1.y); av[11]=hi2f(r1.y);
            av[12]=lo2f(r1.z);
            const float wA = w2[q0*192 + o*3 + 0];
            const float wB = w2[q0*192 + o*3 + 1];
            const float wC = w2[q0*192 + o*3 + 2];
#pragma unroll
            for (int p = 0; p < 11; ++p)
                acc0[p] += wA*av[p] + wB*av[p+1] + wC*av[p+2];
            if (is0) {
                const float wD = w2[q1*192 + o*3 + 0];
                const float wE = w2[q1*192 + o*3 + 1];
                const float wF = w2[q1*192 + o*3 + 2];
#pragma unroll
                for (int p = 0; p < 11; ++p)
                    acc1[p] += wD*av[p] + wE*av[p+1] + wF*av[p+2];
            }
        }
        float* ob = out + (bb + b)*220;
        if (has0) {
            const float bi = cb2[q0];
            const float iv = g2[q0] * rsqrtf(vr2[q0] + 1e-5f);
            const float sh = bt2[q0] - mn2[q0]*iv;
#pragma unroll
            for (int p = 0; p < 11; ++p) {
                float t = (acc0[p] + bi)*iv + sh;
                ob[q0*11 + p] = t > 0.f ? t : 0.01f*t;
            }
        }
        if (is0) {
            const float bi = cb2[q1];
            const float iv = g2[q1] * rsqrtf(vr2[q1] + 1e-5f);
            const float sh = bt2[q1] - mn2[q1]*iv;
#pragma unroll
            for (int p = 0; p < 11; ++p) {
                float t = (acc1[p] + bi)*iv + sh;
                ob[q1*11 + p] = t > 0.f ? t : 0.01f*t;
            }
        }
    }
}

extern "C" void kernel_launch(void* const* d_in, const int* in_sizes, int n_in,
                              void* d_out, int out_size, void* d_ws, size_t ws_size,
                              hipStream_t stream) {
    const float* x    = (const float*)d_in[0];
    const float* w0   = (const float*)d_in[1];
    const float* attw = (const float*)d_in[2];
    const float* attb = (const float*)d_in[3];
    const float* w1   = (const float*)d_in[4];
    const float* cb1  = (const float*)d_in[5];
    const float* g1   = (const float*)d_in[6];
    const float* bt1  = (const float*)d_in[7];
    const float* mn1  = (const float*)d_in[8];
    const float* vr1  = (const float*)d_in[9];
    const float* w2   = (const float*)d_in[10];
    const float* cb2  = (const float*)d_in[11];
    const float* g2   = (const float*)d_in[12];
    const float* bt2  = (const float*)d_in[13];
    const float* mn2  = (const float*)d_in[14];
    const float* vr2  = (const float*)d_in[15];

    dim3 grid(NBATCH / BPB);
    dim3 block(THREADS);
    hipLaunchKernelGGL(peptide_fused, grid, block, 0, stream,
                       x, w0, attw, attb,
                       w1, cb1, g1, bt1, mn1, vr1,
                       w2, cb2, g2, bt2, mn2, vr2,
                       (float*)d_out);
}

// Round 3
// 288.329 us; speedup vs baseline: 3.0460x; 3.0460x over previous
//
#include <hip/hip_runtime.h>

#define THREADS 128
#define BPB 16
#define NBATCH 131072

typedef __attribute__((ext_vector_type(8))) _Float16 half8;
typedef __attribute__((ext_vector_type(4))) float f32x4;

// LDS geometry (bytes):
//  region A [0 .. 29952): x f32 [16][348 dw] (stage 0-1) -> then a1 f16 [16][13][72] (stage 2-3)
//  region Y [29952 .. 49152): y f16 [16][15][40]
#define XB_DW 348            // x batch stride in dwords (multiple of 4: no 16B slot straddles batches)
#define XSLOTS 1392          // 16*348/4 16B-slots
#define A1_BS 1872           // a1 batch stride bytes (117 16B-units, odd)
#define A1_RS 144            // a1 row stride bytes (9 16B-units, odd)
#define Y_BS 1200            // y batch stride bytes (75 units, odd)
#define Y_RS 80              // y row stride bytes (5 units, odd)
#define Y_OFF 29952
#define SMEM_BYTES 49152
#define INV2048 4.8828125e-4f

static __device__ __forceinline__ unsigned short f2h(float f) {
    return __builtin_bit_cast(unsigned short, (_Float16)f);   // RNE
}
static __device__ __forceinline__ unsigned int pack2h(float a, float b) {
    return (unsigned int)f2h(a) | ((unsigned int)f2h(b) << 16);
}

__global__ __launch_bounds__(THREADS, 2)
void peptide_mfma(const float* __restrict__ x,
                  const float* __restrict__ w0,     // [32][21]
                  const float* __restrict__ attw,   // [15][32]
                  const float* __restrict__ attb,   // [15]
                  const float* __restrict__ w1,     // [64][32][3]
                  const float* __restrict__ cb1,
                  const float* __restrict__ g1, const float* __restrict__ bt1,
                  const float* __restrict__ mn1, const float* __restrict__ vr1,
                  const float* __restrict__ w2,     // [20][64][3]
                  const float* __restrict__ cb2,
                  const float* __restrict__ g2, const float* __restrict__ bt2,
                  const float* __restrict__ mn2, const float* __restrict__ vr2,
                  float* __restrict__ out)          // [B][20][11]
{
    __shared__ __align__(16) char smem[SMEM_BYTES];
    float* sx  = (float*)smem;
    char*  sa1 = smem;
    char*  sy  = smem + Y_OFF;

    const int tid  = threadIdx.x;
    const int lane = tid & 63;
    const int wv   = tid >> 6;
    const int bb   = blockIdx.x * BPB;

    // ---------------- stage 0: x -> LDS (f32, batch stride 348 dw) ----------------
    if (blockIdx.x != (int)gridDim.x - 1) {
        const float* xg = x + bb * 315;
        #pragma unroll
        for (int j = 0; j < 11; ++j) {
            const int chunk = j*2 + wv;
            const int slot  = chunk*64 + lane;
            if (slot < XSLOTS) {
                unsigned b  = (unsigned)slot / 87u;          // 87 slots (348 dw) per batch
                unsigned w4 = ((unsigned)slot - b*87u) * 4u; // dword offset in batch, mult of 4
                const float* src = xg + b*315u + ((w4 < 315u) ? w4 : 0u);
                __builtin_amdgcn_global_load_lds(
                    (const __attribute__((address_space(1))) unsigned int*)src,
                    (__attribute__((address_space(3))) unsigned int*)(smem + chunk*1024),
                    16, 0, 0);
            }
        }
        asm volatile("s_waitcnt vmcnt(0)" ::: "memory");
    } else {
        const float* xg = x + bb * 315;
        for (int i = tid; i < BPB*315; i += THREADS) {
            int b = i / 315;
            int r = i - b*315;
            sx[b*XB_DW + r] = xg[i];
        }
    }
    __syncthreads();

    // ---------------- stage 1: conv0 (21->32) + attention softmax -> y f16 [b][p][40B] ----------------
    {
        const int b = tid >> 3;          // batch 0..15
        const int t = tid & 7;           // positions t and t+8 (t==7 -> pad row 15 skipped)
        const float* xrow = sx + b*XB_DW;
        float xa[21], xb[21];
        #pragma unroll
        for (int k = 0; k < 21; ++k) {
            xa[k] = xrow[k*15 + t];
            xb[k] = xrow[k*15 + t + 8];
        }
        float h0[32], h1[32];
        #pragma unroll 4
        for (int c = 0; c < 32; ++c) {
            float s0 = 0.f, s1 = 0.f;
            #pragma unroll
            for (int k = 0; k < 21; ++k) {
                const float wc = w0[c*21 + k];   // block-uniform -> s_load
                s0 = fmaf(wc, xa[k], s0);
                s1 = fmaf(wc, xb[k], s1);
            }
            h0[c] = s0; h1[c] = s1;
        }
        const int l1 = t + 8;
        float lg0 = attb[t];
        float lg1 = (t < 7) ? attb[l1] : 0.f;
        const float* ar0 = attw + t*32;
        const float* ar1 = attw + ((t < 7) ? l1 : 0)*32;
        #pragma unroll
        for (int i = 0; i < 8; ++i) {
            float4 a0  = *(const float4*)(ar0 + 4*i);
            float4 a1v = *(const float4*)(ar1 + 4*i);
            lg0 = fmaf(a0.x,  h0[4*i+0], lg0); lg0 = fmaf(a0.y,  h0[4*i+1], lg0);
            lg0 = fmaf(a0.z,  h0[4*i+2], lg0); lg0 = fmaf(a0.w,  h0[4*i+3], lg0);
            lg1 = fmaf(a1v.x, h1[4*i+0], lg1); lg1 = fmaf(a1v.y, h1[4*i+1], lg1);
            lg1 = fmaf(a1v.z, h1[4*i+2], lg1); lg1 = fmaf(a1v.w, h1[4*i+3], lg1);
        }
        if (t == 7) lg1 = -3.0e38f;
        float mx = fmaxf(lg0, lg1);
        mx = fmaxf(mx, __shfl_xor(mx, 1, 64));
        mx = fmaxf(mx, __shfl_xor(mx, 2, 64));
        mx = fmaxf(mx, __shfl_xor(mx, 4, 64));
        float e0 = __expf(lg0 - mx);
        float e1 = (t == 7) ? 0.f : __expf(lg1 - mx);
        float sm = e0 + e1;
        sm += __shfl_xor(sm, 1, 64);
        sm += __shfl_xor(sm, 2, 64);
        sm += __shfl_xor(sm, 4, 64);
        const float inv = 1.f / sm;
        const float sa = e0 * inv, sb = e1 * inv;

        char* yb = sy + b*Y_BS + t*Y_RS;
        #pragma unroll
        for (int q = 0; q < 4; ++q) {
            uint2 u;
            u.x = pack2h(h0[8*q+0]*sa, h0[8*q+1]*sa);
            u.y = pack2h(h0[8*q+2]*sa, h0[8*q+3]*sa);
            *(uint2*)(yb + q*16) = u;
            u.x = pack2h(h0[8*q+4]*sa, h0[8*q+5]*sa);
            u.y = pack2h(h0[8*q+6]*sa, h0[8*q+7]*sa);
            *(uint2*)(yb + q*16 + 8) = u;
        }
        if (t < 7) {
            char* yc = sy + b*Y_BS + l1*Y_RS;
            #pragma unroll
            for (int q = 0; q < 4; ++q) {
                uint2 u;
                u.x = pack2h(h1[8*q+0]*sb, h1[8*q+1]*sb);
                u.y = pack2h(h1[8*q+2]*sb, h1[8*q+3]*sb);
                *(uint2*)(yc + q*16) = u;
                u.x = pack2h(h1[8*q+4]*sb, h1[8*q+5]*sb);
                u.y = pack2h(h1[8*q+6]*sb, h1[8*q+7]*sb);
                *(uint2*)(yc + q*16 + 8) = u;
            }
        }
    }
    __syncthreads();

    const int col = lane & 15;   // batch column (B/C) ; output-channel row (A)
    const int g   = lane >> 4;   // k-slice group

    // ---------------- stage 2: conv1 (32->64,k3) MFMA f16 (hi/lo split) + bn1 + lrelu -> a1 f16 ----------------
    {
        half8 afh[4][3], afl[4][3];
        #pragma unroll
        for (int mt = 0; mt < 4; ++mt) {
            const int o = mt*16 + col;
            const float* wp = w1 + o*96 + g*24;      // 8 channels x 3 taps, consecutive
            float f[24];
            #pragma unroll
            for (int q = 0; q < 6; ++q) {
                float4 v = *(const float4*)(wp + 4*q);
                f[4*q+0] = v.x; f[4*q+1] = v.y; f[4*q+2] = v.z; f[4*q+3] = v.w;
            }
            #pragma unroll
            for (int s = 0; s < 3; ++s) {
                half8 fh, fl;
                #pragma unroll
                for (int j = 0; j < 8; ++j) {
                    float w = f[j*3 + s];
                    _Float16 h = (_Float16)w;
                    fh[j] = h;
                    fl[j] = (_Float16)((w - (float)h) * 2048.f);
                }
                afh[mt][s] = fh; afl[mt][s] = fl;
            }
        }
        float iva[16], sha[16];
        #pragma unroll
        for (int mt = 0; mt < 4; ++mt) {
            const int o0 = mt*16 + 4*g;
            float4 gg = *(const float4*)(g1 + o0);
            float4 vv = *(const float4*)(vr1 + o0);
            float4 bv = *(const float4*)(bt1 + o0);
            float4 mv = *(const float4*)(mn1 + o0);
            float4 cv = *(const float4*)(cb1 + o0);
            float i0 = gg.x * rsqrtf(vv.x + 1e-5f);
            float i1 = gg.y * rsqrtf(vv.y + 1e-5f);
            float i2 = gg.z * rsqrtf(vv.z + 1e-5f);
            float i3 = gg.w * rsqrtf(vv.w + 1e-5f);
            iva[mt*4+0] = i0; sha[mt*4+0] = bv.x + (cv.x - mv.x)*i0;
            iva[mt*4+1] = i1; sha[mt*4+1] = bv.y + (cv.y - mv.y)*i1;
            iva[mt*4+2] = i2; sha[mt*4+2] = bv.z + (cv.z - mv.z)*i2;
            iva[mt*4+3] = i3; sha[mt*4+3] = bv.w + (cv.w - mv.w)*i3;
        }
        const int p0 = wv ? 7 : 0;
        const int p1 = wv ? 13 : 7;
        const char* ybase = sy + col*Y_BS;
        for (int p = p0; p < p1; ++p) {
            half8 bf0 = *(const half8*)(ybase + (p+0)*Y_RS + g*16);
            half8 bf1 = *(const half8*)(ybase + (p+1)*Y_RS + g*16);
            half8 bf2 = *(const half8*)(ybase + (p+2)*Y_RS + g*16);
            #pragma unroll
            for (int mt = 0; mt < 4; ++mt) {
                f32x4 acc = {0.f, 0.f, 0.f, 0.f};
                f32x4 acl = {0.f, 0.f, 0.f, 0.f};
                acc = __builtin_amdgcn_mfma_f32_16x16x32_f16(afh[mt][0], bf0, acc, 0, 0, 0);
                acc = __builtin_amdgcn_mfma_f32_16x16x32_f16(afh[mt][1], bf1, acc, 0, 0, 0);
                acc = __builtin_amdgcn_mfma_f32_16x16x32_f16(afh[mt][2], bf2, acc, 0, 0, 0);
                acl = __builtin_amdgcn_mfma_f32_16x16x32_f16(afl[mt][0], bf0, acl, 0, 0, 0);
                acl = __builtin_amdgcn_mfma_f32_16x16x32_f16(afl[mt][1], bf1, acl, 0, 0, 0);
                acl = __builtin_amdgcn_mfma_f32_16x16x32_f16(afl[mt][2], bf2, acl, 0, 0, 0);
                float c0 = fmaf(acl[0], INV2048, acc[0]);
                float c1 = fmaf(acl[1], INV2048, acc[1]);
                float c2 = fmaf(acl[2], INV2048, acc[2]);
                float c3 = fmaf(acl[3], INV2048, acc[3]);
                float z0 = fmaf(c0, iva[mt*4+0], sha[mt*4+0]); z0 = fmaxf(z0, 0.01f*z0);
                float z1 = fmaf(c1, iva[mt*4+1], sha[mt*4+1]); z1 = fmaxf(z1, 0.01f*z1);
                float z2 = fmaf(c2, iva[mt*4+2], sha[mt*4+2]); z2 = fmaxf(z2, 0.01f*z2);
                float z3 = fmaf(c3, iva[mt*4+3], sha[mt*4+3]); z3 = fmaxf(z3, 0.01f*z3);
                uint2 u; u.x = pack2h(z0, z1); u.y = pack2h(z2, z3);
                *(uint2*)(sa1 + col*A1_BS + p*A1_RS + mt*32 + g*8) = u;
            }
        }
    }
    __syncthreads();

    // ---------------- stage 3: conv2 (64->20,k3) MFMA f16 (hi/lo split) + bn2 + lrelu -> out ----------------
    {
        half8 afh[2][6], afl[2][6];
        #pragma unroll
        for (int mt = 0; mt < 2; ++mt) {
            const int o = mt*16 + col;
            if (o < 20) {
                #pragma unroll
                for (int h = 0; h < 2; ++h) {
                    const float* wp = w2 + o*192 + h*96 + g*24;
                    float f[24];
                    #pragma unroll
                    for (int q = 0; q < 6; ++q) {
                        float4 v = *(const float4*)(wp + 4*q);
                        f[4*q+0] = v.x; f[4*q+1] = v.y; f[4*q+2] = v.z; f[4*q+3] = v.w;
                    }
                    #pragma unroll
                    for (int tap = 0; tap < 3; ++tap) {
                        half8 fh, fl;
                        #pragma unroll
                        for (int j = 0; j < 8; ++j) {
                            float w = f[j*3 + tap];
                            _Float16 hh2 = (_Float16)w;
                            fh[j] = hh2;
                            fl[j] = (_Float16)((w - (float)hh2) * 2048.f);
                        }
                        afh[mt][tap*2 + h] = fh; afl[mt][tap*2 + h] = fl;
                    }
                }
            } else {
                #pragma unroll
                for (int s = 0; s < 6; ++s) {
                    half8 z; 
                    #pragma unroll
                    for (int j = 0; j < 8; ++j) z[j] = (_Float16)0.f;
                    afh[mt][s] = z; afl[mt][s] = z;
                }
            }
        }
        float iva[8], sha[8];
        #pragma unroll
        for (int mt = 0; mt < 2; ++mt) {
            const int o0 = mt*16 + 4*g;
            if (o0 < 20) {
                float4 gg = *(const float4*)(g2 + o0);
                float4 vv = *(const float4*)(vr2 + o0);
                float4 bv = *(const float4*)(bt2 + o0);
                float4 mv = *(const float4*)(mn2 + o0);
                float4 cv = *(const float4*)(cb2 + o0);
                float i0 = gg.x * rsqrtf(vv.x + 1e-5f);
                float i1 = gg.y * rsqrtf(vv.y + 1e-5f);
                float i2 = gg.z * rsqrtf(vv.z + 1e-5f);
                float i3 = gg.w * rsqrtf(vv.w + 1e-5f);
                iva[mt*4+0] = i0; sha[mt*4+0] = bv.x + (cv.x - mv.x)*i0;
                iva[mt*4+1] = i1; sha[mt*4+1] = bv.y + (cv.y - mv.y)*i1;
                iva[mt*4+2] = i2; sha[mt*4+2] = bv.z + (cv.z - mv.z)*i2;
                iva[mt*4+3] = i3; sha[mt*4+3] = bv.w + (cv.w - mv.w)*i3;
            } else {
                #pragma unroll
                for (int r = 0; r < 4; ++r) { iva[mt*4+r] = 0.f; sha[mt*4+r] = 0.f; }
            }
        }
        const int p0 = wv ? 6 : 0;
        const int p1 = wv ? 11 : 6;
        const char* abase = sa1 + col*A1_BS;
        for (int p = p0; p < p1; ++p) {
            half8 bfr[6];
            #pragma unroll
            for (int s = 0; s < 6; ++s) {
                const int tap = s >> 1, hh = s & 1;
                bfr[s] = *(const half8*)(abase + (p+tap)*A1_RS + hh*64 + g*16);
            }
            float* ob = out + (bb + col)*220 + p;
            #pragma unroll
            for (int mt = 0; mt < 2; ++mt) {
                f32x4 acc = {0.f, 0.f, 0.f, 0.f};
                f32x4 acl = {0.f, 0.f, 0.f, 0.f};
                #pragma unroll
                for (int s = 0; s < 6; ++s)
                    acc = __builtin_amdgcn_mfma_f32_16x16x32_f16(afh[mt][s], bfr[s], acc, 0, 0, 0);
                #pragma unroll
                for (int s = 0; s < 6; ++s)
                    acl = __builtin_amdgcn_mfma_f32_16x16x32_f16(afl[mt][s], bfr[s], acl, 0, 0, 0);
                #pragma unroll
                for (int r = 0; r < 4; ++r) {
                    const int o = mt*16 + 4*g + r;
                    if (o < 20) {
                        float cc = fmaf(acl[r], INV2048, acc[r]);
                        float tv = fmaf(cc, iva[mt*4+r], sha[mt*4+r]);
                        tv = fmaxf(tv, 0.01f*tv);
                        ob[o*11] = tv;
                    }
                }
            }
        }
    }
}

extern "C" void kernel_launch(void* const* d_in, const int* in_sizes, int n_in,
                              void* d_out, int out_size, void* d_ws, size_t ws_size,
                              hipStream_t stream) {
    const float* x    = (const float*)d_in[0];
    const float* w0   = (const float*)d_in[1];
    const float* attw = (const float*)d_in[2];
    const float* attb = (const float*)d_in[3];
    const float* w1   = (const float*)d_in[4];
    const float* cb1  = (const float*)d_in[5];
    const float* g1   = (const float*)d_in[6];
    const float* bt1  = (const float*)d_in[7];
    const float* mn1  = (const float*)d_in[8];
    const float* vr1  = (const float*)d_in[9];
    const float* w2   = (const float*)d_in[10];
    const float* cb2  = (const float*)d_in[11];
    const float* g2   = (const float*)d_in[12];
    const float* bt2  = (const float*)d_in[13];
    const float* mn2  = (const float*)d_in[14];
    const float* vr2  = (const float*)d_in[15];

    dim3 grid(NBATCH / BPB);
    dim3 block(THREADS);
    hipLaunchKernelGGL(peptide_mfma, grid, block, 0, stream,
                       x, w0, attw, attb,
                       w1, cb1, g1, bt1, mn1, vr1,
                       w2, cb2, g2, bt2, mn2, vr2,
                       (float*)d_out);
}

// Round 4
// 262.602 us; speedup vs baseline: 3.3444x; 1.0980x over previous
//
#include <hip/hip_runtime.h>

#define THREADS 128
#define BPB 16
#define NBATCH 131072

typedef __attribute__((ext_vector_type(8))) _Float16 half8;
typedef __attribute__((ext_vector_type(4))) float f32x4;

// LDS geometry (bytes):
//  [0 .. 20224):      x f32 [16][316 dw]  (stages 0-1)   -> reused as out f32 [16][228 dw] (stage 3+copy)
//  [20224 .. 39424):  y f16 [16][15 rows][80B]           (stages 1-2)
#define XB_DW 316            // x batch stride in dwords (mult of 4: 16B slots never straddle batches)
#define XSLOTS 1264          // 16 * 79 slots
#define Y_OFF 20224
#define Y_RS 80              // y row stride bytes (5 16B-units, odd -> bank stagger)
#define Y_BS 1200            // y batch stride bytes (75 units, odd)
#define SMEM_BYTES 39424
#define OUT_SDW 228          // out staging batch stride in dwords (57 16B-units)

static __device__ __forceinline__ unsigned short f2h(float f) {
    return __builtin_bit_cast(unsigned short, (_Float16)f);   // RNE
}
static __device__ __forceinline__ unsigned int pack2h(float a, float b) {
    return (unsigned int)f2h(a) | ((unsigned int)f2h(b) << 16);
}

// Merged conv1(+bn1+lrelu) -> registers -> conv2(+bn2+lrelu) -> LDS out staging.
// Stage-2 output channels are PERMUTED across C-rows so each lane's accumulators
// are exactly the channels its stage-3 B-fragments need (no cross-lane traffic):
//   channel(mt, row) = 32*(mt>>1) + 8*(row>>2) + 4*(mt&1) + (row&3)
// => lane g holds channels {8g..8g+7} u {32+8g..32+8g+7} = B-frag k-slices.
template<int R0, int NR, int P0, int NP>
__device__ __forceinline__ void stack23(
    const char* __restrict__ sy, float* __restrict__ sout,
    const int col, const int g,
    const float* __restrict__ w1, const float* __restrict__ cb1,
    const float* __restrict__ g1, const float* __restrict__ bt1,
    const float* __restrict__ mn1, const float* __restrict__ vr1,
    const float* __restrict__ w2, const float* __restrict__ cb2,
    const float* __restrict__ g2, const float* __restrict__ bt2,
    const float* __restrict__ mn2, const float* __restrict__ vr2)
{
    // ---- A-fragments for conv1 (iva1 baked into weights; A row = permuted channel) ----
    half8 af2[4][3];
    #pragma unroll
    for (int mt = 0; mt < 4; ++mt) {
        const int o = 32*(mt>>1) + 8*(col>>2) + 4*(mt&1) + (col&3);
        const float iva = g1[o] * rsqrtf(vr1[o] + 1e-5f);
        const float* wp = w1 + o*96 + g*24;          // 8 in-channels x 3 taps
        float f[24];
        #pragma unroll
        for (int q = 0; q < 6; ++q) {
            float4 v = *(const float4*)(wp + 4*q);
            f[4*q+0]=v.x; f[4*q+1]=v.y; f[4*q+2]=v.z; f[4*q+3]=v.w;
        }
        #pragma unroll
        for (int s = 0; s < 3; ++s) {
            half8 fh;
            #pragma unroll
            for (int j = 0; j < 8; ++j) fh[j] = (_Float16)(f[j*3+s] * iva);
            af2[mt][s] = fh;
        }
    }
    float sha1v[16];
    #pragma unroll
    for (int mt = 0; mt < 4; ++mt)
    #pragma unroll
    for (int r = 0; r < 4; ++r) {
        const int o = 32*(mt>>1) + 8*g + 4*(mt&1) + r;   // C-row 4g+r holds this channel
        const float iva = g1[o] * rsqrtf(vr1[o] + 1e-5f);
        sha1v[mt*4+r] = bt1[o] + (cb1[o] - mn1[o]) * iva;
    }

    // ---- row phase: a1 rows R0..R0+NR-1 -> register B-fragments fr[i][h] ----
    half8 fr[NR][2];
    {
        const char* yb = sy + col*Y_BS;
        half8 y3[3];
        y3[(R0+0) % 3] = *(const half8*)(yb + (R0+0)*Y_RS + g*16);
        y3[(R0+1) % 3] = *(const half8*)(yb + (R0+1)*Y_RS + g*16);
        #pragma unroll
        for (int i = 0; i < NR; ++i) {
            const int r = R0 + i;
            y3[(r+2) % 3] = *(const half8*)(yb + (r+2)*Y_RS + g*16);
            f32x4 acc0 = {0.f,0.f,0.f,0.f}, acc1 = {0.f,0.f,0.f,0.f};
            f32x4 acc2 = {0.f,0.f,0.f,0.f}, acc3 = {0.f,0.f,0.f,0.f};
            #pragma unroll
            for (int s = 0; s < 3; ++s) {
                const half8 yy = y3[(r+s) % 3];
                acc0 = __builtin_amdgcn_mfma_f32_16x16x32_f16(af2[0][s], yy, acc0, 0,0,0);
                acc1 = __builtin_amdgcn_mfma_f32_16x16x32_f16(af2[1][s], yy, acc1, 0,0,0);
                acc2 = __builtin_amdgcn_mfma_f32_16x16x32_f16(af2[2][s], yy, acc2, 0,0,0);
                acc3 = __builtin_amdgcn_mfma_f32_16x16x32_f16(af2[3][s], yy, acc3, 0,0,0);
            }
            float z[4][4];
            #pragma unroll
            for (int r2 = 0; r2 < 4; ++r2) {
                float t0 = acc0[r2] + sha1v[ 0+r2]; z[0][r2] = fmaxf(t0, 0.01f*t0);
                float t1 = acc1[r2] + sha1v[ 4+r2]; z[1][r2] = fmaxf(t1, 0.01f*t1);
                float t2 = acc2[r2] + sha1v[ 8+r2]; z[2][r2] = fmaxf(t2, 0.01f*t2);
                float t3 = acc3[r2] + sha1v[12+r2]; z[3][r2] = fmaxf(t3, 0.01f*t3);
            }
            // frag h elements j: j=0..3 from mt=2h (r=j), j=4..7 from mt=2h+1
            uint4 u0, u1;
            u0.x = pack2h(z[0][0], z[0][1]); u0.y = pack2h(z[0][2], z[0][3]);
            u0.z = pack2h(z[1][0], z[1][1]); u0.w = pack2h(z[1][2], z[1][3]);
            u1.x = pack2h(z[2][0], z[2][1]); u1.y = pack2h(z[2][2], z[2][3]);
            u1.z = pack2h(z[3][0], z[3][1]); u1.w = pack2h(z[3][2], z[3][3]);
            fr[i][0] = __builtin_bit_cast(half8, u0);
            fr[i][1] = __builtin_bit_cast(half8, u1);
        }
    }

    // ---- p phase: conv2 from register fragments ----
    half8 af3[2][6];
    #pragma unroll
    for (int mt = 0; mt < 2; ++mt) {
        const int o = mt*16 + col;
        if (o < 20) {
            const float iva = g2[o] * rsqrtf(vr2[o] + 1e-5f);
            #pragma unroll
            for (int h = 0; h < 2; ++h) {
                const float* wp = w2 + o*192 + h*96 + g*24;
                float f[24];
                #pragma unroll
                for (int q = 0; q < 6; ++q) {
                    float4 v = *(const float4*)(wp + 4*q);
                    f[4*q+0]=v.x; f[4*q+1]=v.y; f[4*q+2]=v.z; f[4*q+3]=v.w;
                }
                #pragma unroll
                for (int tap = 0; tap < 3; ++tap) {
                    half8 fh;
                    #pragma unroll
                    for (int j = 0; j < 8; ++j) fh[j] = (_Float16)(f[j*3+tap] * iva);
                    af3[mt][tap*2 + h] = fh;
                }
            }
        } else {
            #pragma unroll
            for (int s = 0; s < 6; ++s) {
                half8 zf;
                #pragma unroll
                for (int j = 0; j < 8; ++j) zf[j] = (_Float16)0.f;
                af3[mt][s] = zf;
            }
        }
    }
    float sha2v[8];
    #pragma unroll
    for (int mt = 0; mt < 2; ++mt)
    #pragma unroll
    for (int r = 0; r < 4; ++r) {
        const int o = mt*16 + 4*g + r;
        if (o < 20) {
            const float iva = g2[o] * rsqrtf(vr2[o] + 1e-5f);
            sha2v[mt*4+r] = bt2[o] + (cb2[o] - mn2[o]) * iva;
        } else sha2v[mt*4+r] = 0.f;
    }

    #pragma unroll
    for (int pp = 0; pp < NP; ++pp) {
        const int p = P0 + pp;
        f32x4 acc0 = {0.f,0.f,0.f,0.f}, acc1 = {0.f,0.f,0.f,0.f};
        #pragma unroll
        for (int s = 0; s < 6; ++s) {
            const half8 bf = fr[pp + (s>>1)][s & 1];
            acc0 = __builtin_amdgcn_mfma_f32_16x16x32_f16(af3[0][s], bf, acc0, 0,0,0);
            acc1 = __builtin_amdgcn_mfma_f32_16x16x32_f16(af3[1][s], bf, acc1, 0,0,0);
        }
        #pragma unroll
        for (int r = 0; r < 4; ++r) {
            const int o0 = 4*g + r;                       // < 16: always valid
            float t0 = acc0[r] + sha2v[r];
            t0 = fmaxf(t0, 0.01f*t0);
            sout[col*OUT_SDW + o0*11 + p] = t0;
            const int o1 = 16 + 4*g + r;
            if (o1 < 20) {
                float t1 = acc1[r] + sha2v[4+r];
                t1 = fmaxf(t1, 0.01f*t1);
                sout[col*OUT_SDW + o1*11 + p] = t1;
            }
        }
    }
}

__global__ __launch_bounds__(THREADS, 2)
void peptide_mfma2(const float* __restrict__ x,
                   const float* __restrict__ w0,     // [32][21]
                   const float* __restrict__ attw,   // [15][32]
                   const float* __restrict__ attb,   // [15]
                   const float* __restrict__ w1,     // [64][32][3]
                   const float* __restrict__ cb1,
                   const float* __restrict__ g1, const float* __restrict__ bt1,
                   const float* __restrict__ mn1, const float* __restrict__ vr1,
                   const float* __restrict__ w2,     // [20][64][3]
                   const float* __restrict__ cb2,
                   const float* __restrict__ g2, const float* __restrict__ bt2,
                   const float* __restrict__ mn2, const float* __restrict__ vr2,
                   float* __restrict__ out)          // [B][20][11]
{
    __shared__ __align__(16) char smem[SMEM_BYTES];
    float* sx   = (float*)smem;
    float* sout = (float*)smem;
    char*  sy   = smem + Y_OFF;

    const int tid  = threadIdx.x;
    const int lane = tid & 63;
    const int wv   = tid >> 6;
    const int bb   = blockIdx.x * BPB;

    // ---------------- stage 0: x -> LDS ----------------
    if (blockIdx.x != (int)gridDim.x - 1) {
        const float* xg = x + (size_t)bb * 315;
        #pragma unroll
        for (int j = 0; j < 10; ++j) {
            const int chunk = j*2 + wv;
            const int slot  = chunk*64 + lane;
            if (slot < XSLOTS) {
                unsigned b  = ((unsigned)slot * 830u) >> 16;     // slot / 79
                unsigned w4 = ((unsigned)slot - b*79u) * 4u;
                const float* src = xg + b*315u + w4;             // may poke pad region: valid mem
                __builtin_amdgcn_global_load_lds(
                    (const __attribute__((address_space(1))) unsigned int*)src,
                    (__attribute__((address_space(3))) unsigned int*)(smem + chunk*1024),
                    16, 0, 0);
            }
        }
        asm volatile("s_waitcnt vmcnt(0)" ::: "memory");
    } else {
        const float* xg = x + (size_t)bb * 315;
        for (int i = tid; i < BPB*315; i += THREADS) {
            int b = i / 315;
            int r = i - b*315;
            sx[b*XB_DW + r] = xg[i];
        }
    }
    __syncthreads();

    // ---------------- stage 1: conv0 (21->32) + attention softmax -> y f16 ----------------
    {
        const int b = tid >> 3;          // batch 0..15
        const int t = tid & 7;           // positions t and t+8 (t==7: row 15 is pad, skipped)
        const float* xrow = sx + b*XB_DW;
        float xa[21], xb[21];
        #pragma unroll
        for (int k = 0; k < 21; ++k) {
            xa[k] = xrow[k*15 + t];
            xb[k] = xrow[k*15 + t + 8];
        }
        float h0[32], h1[32];
        #pragma unroll 4
        for (int c = 0; c < 32; ++c) {
            float s0 = 0.f, s1 = 0.f;
            #pragma unroll
            for (int k = 0; k < 21; ++k) {
                const float wc = w0[c*21 + k];   // block-uniform -> s_load
                s0 = fmaf(wc, xa[k], s0);
                s1 = fmaf(wc, xb[k], s1);
            }
            h0[c] = s0; h1[c] = s1;
        }
        const int l1 = t + 8;
        float lg0 = attb[t];
        float lg1 = (t < 7) ? attb[l1] : 0.f;
        const float* ar0 = attw + t*32;
        const float* ar1 = attw + ((t < 7) ? l1 : 0)*32;
        #pragma unroll
        for (int i = 0; i < 8; ++i) {
            float4 a0  = *(const float4*)(ar0 + 4*i);
            float4 a1v = *(const float4*)(ar1 + 4*i);
            lg0 = fmaf(a0.x,  h0[4*i+0], lg0); lg0 = fmaf(a0.y,  h0[4*i+1], lg0);
            lg0 = fmaf(a0.z,  h0[4*i+2], lg0); lg0 = fmaf(a0.w,  h0[4*i+3], lg0);
            lg1 = fmaf(a1v.x, h1[4*i+0], lg1); lg1 = fmaf(a1v.y, h1[4*i+1], lg1);
            lg1 = fmaf(a1v.z, h1[4*i+2], lg1); lg1 = fmaf(a1v.w, h1[4*i+3], lg1);
        }
        if (t == 7) lg1 = -3.0e38f;
        float mx = fmaxf(lg0, lg1);
        mx = fmaxf(mx, __shfl_xor(mx, 1, 64));
        mx = fmaxf(mx, __shfl_xor(mx, 2, 64));
        mx = fmaxf(mx, __shfl_xor(mx, 4, 64));
        float e0 = __expf(lg0 - mx);
        float e1 = (t == 7) ? 0.f : __expf(lg1 - mx);
        float sm = e0 + e1;
        sm += __shfl_xor(sm, 1, 64);
        sm += __shfl_xor(sm, 2, 64);
        sm += __shfl_xor(sm, 4, 64);
        const float inv = 1.f / sm;
        const float sa = e0 * inv, sb = e1 * inv;

        char* yb = sy + b*Y_BS + t*Y_RS;
        #pragma unroll
        for (int q = 0; q < 4; ++q) {
            uint2 u;
            u.x = pack2h(h0[8*q+0]*sa, h0[8*q+1]*sa);
            u.y = pack2h(h0[8*q+2]*sa, h0[8*q+3]*sa);
            *(uint2*)(yb + q*16) = u;
            u.x = pack2h(h0[8*q+4]*sa, h0[8*q+5]*sa);
            u.y = pack2h(h0[8*q+6]*sa, h0[8*q+7]*sa);
            *(uint2*)(yb + q*16 + 8) = u;
        }
        if (t < 7) {
            char* yc = sy + b*Y_BS + l1*Y_RS;
            #pragma unroll
            for (int q = 0; q < 4; ++q) {
                uint2 u;
                u.x = pack2h(h1[8*q+0]*sb, h1[8*q+1]*sb);
                u.y = pack2h(h1[8*q+2]*sb, h1[8*q+3]*sb);
                *(uint2*)(yc + q*16) = u;
                u.x = pack2h(h1[8*q+4]*sb, h1[8*q+5]*sb);
                u.y = pack2h(h1[8*q+6]*sb, h1[8*q+7]*sb);
                *(uint2*)(yc + q*16 + 8) = u;
            }
        }
    }
    __syncthreads();   // y complete; x region now dead -> reused as out staging

    // ---------------- stages 2+3 merged, per-wave p-split (rows 6,7 computed twice) ----------------
    {
        const int col = lane & 15;
        const int g   = lane >> 4;
        if (wv == 0)
            stack23<0,8,0,6>(sy, sout, col, g, w1, cb1, g1, bt1, mn1, vr1,
                             w2, cb2, g2, bt2, mn2, vr2);
        else
            stack23<6,7,6,5>(sy, sout, col, g, w1, cb1, g1, bt1, mn1, vr1,
                             w2, cb2, g2, bt2, mn2, vr2);
    }
    __syncthreads();

    // ---------------- coalesced copy: LDS out staging -> global ----------------
    {
        #pragma unroll
        for (int j = 0; j < 8; ++j) {
            const int u = tid + j*THREADS;
            if (u < 912) {                                   // 16 batches x 57 units
                unsigned b = ((unsigned)u * 1150u) >> 16;    // u / 57
                unsigned r = (unsigned)u - b*57u;
                if (r < 55u) {
                    float4 v = *(const float4*)(smem + u*16);
                    *(float4*)(out + (size_t)(bb + b)*220 + r*4) = v;
                }
            }
        }
    }
}

extern "C" void kernel_launch(void* const* d_in, const int* in_sizes, int n_in,
                              void* d_out, int out_size, void* d_ws, size_t ws_size,
                              hipStream_t stream) {
    const float* x    = (const float*)d_in[0];
    const float* w0   = (const float*)d_in[1];
    const float* attw = (const float*)d_in[2];
    const float* attb = (const float*)d_in[3];
    const float* w1   = (const float*)d_in[4];
    const float* cb1  = (const float*)d_in[5];
    const float* g1   = (const float*)d_in[6];
    const float* bt1  = (const float*)d_in[7];
    const float* mn1  = (const float*)d_in[8];
    const float* vr1  = (const float*)d_in[9];
    const float* w2   = (const float*)d_in[10];
    const float* cb2  = (const float*)d_in[11];
    const float* g2   = (const float*)d_in[12];
    const float* bt2  = (const float*)d_in[13];
    const float* mn2  = (const float*)d_in[14];
    const float* vr2  = (const float*)d_in[15];

    dim3 grid(NBATCH / BPB);
    dim3 block(THREADS);
    hipLaunchKernelGGL(peptide_mfma2, grid, block, 0, stream,
                       x, w0, attw, attb,
                       w1, cb1, g1, bt1, mn1, vr1,
                       w2, cb2, g2, bt2, mn2, vr2,
                       (float*)d_out);
}